// Round 4
// baseline (340.880 us; speedup 1.0000x reference)
//
#include <hip/hip_runtime.h>
#include <float.h>
#include <math.h>

// AdvancedLossFunction: total = 1.0*occ + 0.1*smooth + 0.01*sparse + 0.1*cons
// R17: single fused kernel (+ 516-B memset for tickets).
//  - knn: 32-j candidate groups == one MFMA tile. Per tile: balanced 16-way
//    min over acc regs (per-half rows), 1 key pack (23 value bits, 9-bit id),
//    1 ins4f. ~14 VALU/tile vs R16's ~22. Cross-half dedup keeps min of dup
//    ids (R15 coverage proof unchanged: keys <= t(NN3) are needed-group keys,
//    <=4 of them, always in each half's top-4; distinct-id top-4 covers).
//  - fusion: per-ibk ticket (no spin): 16 chunk-blocks write cand[chunk][i],
//    all-thread __threadfence (release), tid0 atomicAdd(ticket[ibk]); 16th
//    arriver merges its 128 i's: thread=(i,half) evaluates 2 of the top-4
//    groups (32 cands each, exact d2, self-excl), halves merged via LDS.
//    part/done last-block pattern does the final reduction (proven on this
//    harness across rounds). Tickets+done zeroed by hipMemsetAsync.
//  - feat reduction folded into the 2048 knn blocks (512 floats each,
//    overlaps staging); deterministic tree (block partials -> final block).
// Fill ~40.5us + ~25-40us of tiny reset dispatches are harness-fixed.

constexpr int   N_ = 16384;
constexpr int   F_ = 64;
constexpr float OCC_W = 1.0f, SMOOTH_W = 0.1f, SPARSE_W = 0.01f, CONS_W = 0.1f;
constexpr float EPS_ = 1e-7f;

constexpr int CHUNKS  = 16;
constexpr int CHUNK_J = N_ / CHUNKS;    // 1024 j's per chunk
constexpr int JTILES  = CHUNK_J / 32;   // 32 tiles = 32 groups per chunk
constexpr int IB      = 128;            // i's per block (4 waves x 32)
constexpr int IBLOCKS = N_ / IB;        // 128

typedef __attribute__((ext_vector_type(8)))  short bf16x8;
typedef __attribute__((ext_vector_type(16))) float f32x16;

union U128 { uint4 u; bf16x8 s; };

__device__ __forceinline__ void ins4f(float t, float& b0, float& b1, float& b2, float& b3) {
  // maintains b0<=b1<=b2<=b3
  float n0 = fminf(b0, t);
  float n1 = __builtin_amdgcn_fmed3f(b0, b1, t);
  float n2 = __builtin_amdgcn_fmed3f(b1, b2, t);
  float n3 = __builtin_amdgcn_fmed3f(b2, b3, t);
  b0 = n0; b1 = n1; b2 = n2; b3 = n3;
}

__device__ __forceinline__ void ins3dp(float d2, float pj,
                                       float& c0, float& c1, float& c2,
                                       float& p0, float& p1, float& p2) {
  if (d2 < c2) {
    bool cc0 = d2 < c0, cc1 = d2 < c1;
    float n2 = cc1 ? c1 : d2;               float m2 = cc1 ? p1 : pj;
    float n1 = cc0 ? c0 : (cc1 ? d2 : c1);  float m1 = cc0 ? p0 : (cc1 ? pj : p1);
    float n0 = cc0 ? d2 : c0;               float m0 = cc0 ? pj : p0;
    c0 = n0; c1 = n1; c2 = n2; p0 = m0; p1 = m1; p2 = m2;
  }
}

// RNE split x = hi + lo (both bf16); returns 16-bit payloads.
__device__ __forceinline__ void split2(float x, unsigned& h16, unsigned& l16) {
  unsigned u = __float_as_uint(x);
  unsigned r = u + 0x7FFFu + ((u >> 16) & 1u);
  h16 = r >> 16;
  float lo = x - __uint_as_float(r & 0xFFFF0000u);
  unsigned v = __float_as_uint(lo);
  l16 = (v + 0x7FFFu + ((v >> 16) & 1u)) >> 16;
}

// ws layout:
//   0     : float4 part[128]
//   4096  : unsigned done
//   4100  : unsigned ticket[128]      (memset 516 B zeroes done+ticket)
//   5120  : float featp[2048]
//   16384 : float4 cand[CHUNKS][N]

__global__ __launch_bounds__(256) void fused_kernel(const float* __restrict__ pred,
                                                    const float* __restrict__ targ,
                                                    const float* __restrict__ feat,
                                                    const float* __restrict__ pts,
                                                    float4* __restrict__ part,
                                                    unsigned* __restrict__ done,
                                                    unsigned* __restrict__ ticket,
                                                    float* __restrict__ featp,
                                                    float4* __restrict__ cand,
                                                    float* __restrict__ out) {
  __shared__ __align__(16) unsigned char smem[32768];
  __shared__ float fws[4];
  __shared__ float ws4[4][4];
  __shared__ int mflag, lflag;

  const int tid   = threadIdx.x;
  const int b     = blockIdx.x;
  const int chunk = b & (CHUNKS - 1);
  const int ibk   = b >> 4;            // log2(CHUNKS)
  const int j0    = chunk * CHUNK_J;
  const int lane  = tid & 63, wv = tid >> 6;
  const int h     = lane >> 5, il = lane & 31;

  // ---- feat partial: 512 floats per block (overlaps staging) ----
  {
    float a = fabsf(feat[b * 512 + tid]) + fabsf(feat[b * 512 + 256 + tid]);
    for (int off = 32; off > 0; off >>= 1) a += __shfl_down(a, off);
    if (lane == 0) fws[wv] = a;
  }

  // ---- stage j-side fragments ----
  uint4 (*AF)[CHUNK_J] = reinterpret_cast<uint4(*)[CHUNK_J]>(smem);
  for (int t = tid; t < CHUNK_J; t += 256) {
    int j = j0 + t;
    float qx = pts[3 * j], qy = pts[3 * j + 1], qz = pts[3 * j + 2];
    float w  = fmaf(qx, qx, fmaf(qy, qy, qz * qz));
    unsigned Hx, Lx, Hy, Ly, Hz, Lz, Hw, Lw;
    split2(-2.f * qx, Hx, Lx);
    split2(-2.f * qy, Hy, Ly);
    split2(-2.f * qz, Hz, Lz);
    split2(w, Hw, Lw);
    AF[0][t] = make_uint4(Hx | (Hx << 16), Lx | (Lx << 16),
                          Hy | (Hy << 16), Ly | (Ly << 16));
    AF[1][t] = make_uint4(Hz | (Hz << 16), Lz | (Lz << 16),
                          Hw | (Lw << 16), 0u);
  }

  // ---- i-side (B operand) fragment ----
  const int i = ibk * IB + wv * 32 + il;
  U128 bfr;
  {
    float x = pts[3 * i], y = pts[3 * i + 1], z = pts[3 * i + 2];
    unsigned hx, lx, hy, ly, hz, lz;
    split2(x, hx, lx);
    split2(y, hy, ly);
    split2(z, hz, lz);
    if (h == 0) {
      unsigned a = hx | (lx << 16), c = hy | (ly << 16);
      bfr.u = make_uint4(a, a, c, c);
    } else {
      unsigned a = hz | (lz << 16);
      bfr.u = make_uint4(a, a, 0x3F803F80u, 0u);   // bf16(1.0) pair
    }
  }
  __syncthreads();
  if (tid == 0) featp[b] = fws[0] + fws[1] + fws[2] + fws[3];

  // ---- knn tile loop: one 32-j group per tile ----
  float b0 = FLT_MAX, b1 = FLT_MAX, b2 = FLT_MAX, b3 = FLT_MAX;
  const f32x16 zacc = {};
  const unsigned idb = (unsigned)(chunk * JTILES);   // group id base, 9 bits total
  const uint4* __restrict__ afp = &AF[h][0];

#pragma unroll 4
  for (int t = 0; t < JTILES; ++t) {
    U128 af; af.u = afp[t * 32 + il];
    f32x16 acc = __builtin_amdgcn_mfma_f32_32x32x16_bf16(af.s, bfr.s, zacc, 0, 0, 0);
    // balanced 16-way min over this lane-half's 16 rows of the tile
    float u0 = fminf(acc[0],  acc[1]),  u1 = fminf(acc[2],  acc[3]);
    float u2 = fminf(acc[4],  acc[5]),  u3 = fminf(acc[6],  acc[7]);
    float u4 = fminf(acc[8],  acc[9]),  u5 = fminf(acc[10], acc[11]);
    float u6 = fminf(acc[12], acc[13]), u7 = fminf(acc[14], acc[15]);
    float v0 = fminf(u0, u1), v1 = fminf(u2, u3);
    float v2 = fminf(u4, u5), v3 = fminf(u6, u7);
    float m  = fminf(fminf(v0, v1), fminf(v2, v3));
    float kf = __uint_as_float((__float_as_uint(m) & 0xFFFFFE00u) | (idb + (unsigned)t));
    ins4f(kf, b0, b1, b2, b3);
  }

  // ---- cross-half merge: halves hold partial minima of the SAME group ids
  // over disjoint row subsets -> dedup keeps the smaller of a dup pair.
  {
    float o0 = __shfl_xor(b0, 32), o1 = __shfl_xor(b1, 32),
          o2 = __shfl_xor(b2, 32), o3 = __shfl_xor(b3, 32);
    float B[4] = {b0, b1, b2, b3};
    float O[4] = {o0, o1, o2, o3};
    unsigned ibd[4], iod[4];
#pragma unroll
    for (int k = 0; k < 4; ++k) {
      ibd[k] = __float_as_uint(B[k]) & 0x1FFu;
      iod[k] = __float_as_uint(O[k]) & 0x1FFu;
    }
#pragma unroll
    for (int k = 0; k < 4; ++k) {
#pragma unroll
      for (int m = 0; m < 4; ++m) {
        bool dup = (iod[k] == ibd[m]);
        bool om  = dup && (O[k] >= B[m]);
        bool bm  = dup && (O[k] <  B[m]);
        if (om) O[k] = FLT_MAX;
        if (bm) B[m] = FLT_MAX;
      }
    }
    b0 = b1 = b2 = b3 = FLT_MAX;
#pragma unroll
    for (int k = 0; k < 4; ++k) ins4f(B[k], b0, b1, b2, b3);
#pragma unroll
    for (int k = 0; k < 4; ++k) ins4f(O[k], b0, b1, b2, b3);
  }
  if (h == 0) cand[(size_t)chunk * N_ + i] = make_float4(b0, b1, b2, b3);

  // ---- release + per-ibk ticket ----
  __threadfence();                       // all threads: flush cand writes device-wide
  __syncthreads();
  if (tid == 0) {
    unsigned prev = atomicAdd(&ticket[ibk], 1u);
    mflag = (prev == (unsigned)(CHUNKS - 1));
  }
  __syncthreads();
  if (!mflag) return;
  __threadfence();                       // acquire: see other blocks' cand

  // ======== merger for this ibk: 128 i's, thread = (ii, half) ========
  float4* pb = reinterpret_cast<float4*>(smem);          // [2][128]
  uint4*  tg = reinterpret_cast<uint4*>(smem + 4096);    // [128]
  float2* t3 = reinterpret_cast<float2*>(smem + 8192);   // [2][3][128]

  const int ii   = tid & 127, half = tid >> 7;
  const int iG   = ibk * IB + ii;

  // phase B: partial top-4 over this half's 8 chunks (ids chunk-disjoint)
  float a0 = FLT_MAX, a1 = FLT_MAX, a2 = FLT_MAX, a3 = FLT_MAX;
#pragma unroll
  for (int cc = 0; cc < 8; ++cc) {
    float4 v = cand[(size_t)(half * 8 + cc) * N_ + iG];
    ins4f(v.x, a0, a1, a2, a3);
    ins4f(v.y, a0, a1, a2, a3);
    ins4f(v.z, a0, a1, a2, a3);
    ins4f(v.w, a0, a1, a2, a3);
  }
  pb[half * 128 + ii] = make_float4(a0, a1, a2, a3);
  __syncthreads();

  // phase C: merge halves (no dup ids across halves) -> top-4 group ids
  if (half == 0) {
    float4 o = pb[128 + ii];
    ins4f(o.x, a0, a1, a2, a3);
    ins4f(o.y, a0, a1, a2, a3);
    ins4f(o.z, a0, a1, a2, a3);
    ins4f(o.w, a0, a1, a2, a3);
    tg[ii] = make_uint4(__float_as_uint(a0) & 0x1FFu, __float_as_uint(a1) & 0x1FFu,
                        __float_as_uint(a2) & 0x1FFu, __float_as_uint(a3) & 0x1FFu);
  }
  __syncthreads();

  // phase D: this thread evaluates 2 of the 4 groups (32 cands each), exact d2
  uint4 g4 = tg[ii];
  unsigned ga = half ? g4.z : g4.x;
  unsigned gb = half ? g4.w : g4.y;
  float xi = pts[3 * iG], yi = pts[3 * iG + 1], zi = pts[3 * iG + 2];
  float c0 = FLT_MAX, c1 = FLT_MAX, c2 = FLT_MAX;
  float p0 = 0.f, p1 = 0.f, p2 = 0.f;
#pragma unroll 1
  for (int gsel = 0; gsel < 2; ++gsel) {
    int jb = (int)(gsel ? gb : ga) * 32;
#pragma unroll 8
    for (int m = 0; m < 32; ++m) {
      int j = jb + m;
      float dx = xi - pts[3 * j], dy = yi - pts[3 * j + 1], dz = zi - pts[3 * j + 2];
      float d2 = fmaf(dx, dx, fmaf(dy, dy, dz * dz));
      float pj = pred[j];
      if (j != iG) ins3dp(d2, pj, c0, c1, c2, p0, p1, p2);
    }
  }
  t3[(half * 3 + 0) * 128 + ii] = make_float2(c0, p0);
  t3[(half * 3 + 1) * 128 + ii] = make_float2(c1, p1);
  t3[(half * 3 + 2) * 128 + ii] = make_float2(c2, p2);
  __syncthreads();

  // phase E: merge halves' top-3 -> final top-3 -> per-i scalars
  float s_occ = 0.f, s_cons = 0.f, s_sm = 0.f;
  if (half == 0) {
#pragma unroll
    for (int r = 0; r < 3; ++r) {
      float2 e = t3[(3 + r) * 128 + ii];
      ins3dp(e.x, e.y, c0, c1, c2, p0, p1, p2);
    }
    float pi = pred[iG], tgv = targ[iG];
    float p  = fminf(fmaxf(pi, EPS_), 1.0f - EPS_);
    s_occ  = -(tgv * __logf(p) + (1.0f - tgv) * __logf(1.0f - p));
    float dd = pi - tgv;
    s_cons = dd * dd;
    s_sm   = fabsf(pi - p0) + fabsf(pi - p1) + fabsf(pi - p2);
  }

  for (int off = 32; off > 0; off >>= 1) {
    s_occ  += __shfl_down(s_occ, off);
    s_cons += __shfl_down(s_cons, off);
    s_sm   += __shfl_down(s_sm, off);
  }
  if (lane == 0) { ws4[wv][0] = s_occ; ws4[wv][1] = s_cons; ws4[wv][2] = s_sm; }
  __syncthreads();
  if (tid == 0) {
    part[ibk] = make_float4(ws4[0][0] + ws4[1][0] + ws4[2][0] + ws4[3][0],
                            ws4[0][1] + ws4[1][1] + ws4[2][1] + ws4[3][1],
                            0.f,
                            ws4[0][2] + ws4[1][2] + ws4[2][2] + ws4[3][2]);
    __threadfence();
    unsigned prev = atomicAdd(done, 1u);
    lflag = (prev == (unsigned)(IBLOCKS - 1));
  }
  __syncthreads();
  if (!lflag) return;
  __threadfence();

  // ======== final block: global reduction ========
  float fo = 0.f, fc = 0.f, fs = 0.f, fp = 0.f;
  if (tid < IBLOCKS) {
    float4 a = part[tid];
    fo = a.x; fc = a.y; fs = a.w;
  }
#pragma unroll
  for (int q = 0; q < 8; ++q) fp += featp[tid * 8 + q];
  for (int off = 32; off > 0; off >>= 1) {
    fo += __shfl_down(fo, off);
    fc += __shfl_down(fc, off);
    fs += __shfl_down(fs, off);
    fp += __shfl_down(fp, off);
  }
  if (lane == 0) { ws4[wv][0] = fo; ws4[wv][1] = fc; ws4[wv][2] = fs; ws4[wv][3] = fp; }
  __syncthreads();
  if (tid == 0) {
    float occ  = ws4[0][0] + ws4[1][0] + ws4[2][0] + ws4[3][0];
    float cons = ws4[0][1] + ws4[1][1] + ws4[2][1] + ws4[3][1];
    float smoo = ws4[0][2] + ws4[1][2] + ws4[2][2] + ws4[3][2];
    float spar = ws4[0][3] + ws4[1][3] + ws4[2][3] + ws4[3][3];
    out[0] = OCC_W * (occ / (float)N_)
           + CONS_W * (cons / (float)N_)
           + SPARSE_W * (spar / (float)(N_ * F_))
           + SMOOTH_W * (smoo / (float)(N_ * 3));
  }
}

extern "C" void kernel_launch(void* const* d_in, const int* in_sizes, int n_in,
                              void* d_out, int out_size, void* d_ws, size_t ws_size,
                              hipStream_t stream) {
  const float* pred = (const float*)d_in[0];
  const float* targ = (const float*)d_in[1];
  const float* feat = (const float*)d_in[2];
  const float* pts  = (const float*)d_in[3];
  float* out = (float*)d_out;

  char*     ws     = (char*)d_ws;
  float4*   part   = (float4*)ws;
  unsigned* done   = (unsigned*)(ws + 4096);
  unsigned* ticket = (unsigned*)(ws + 4100);
  float*    featp  = (float*)(ws + 5120);
  float4*   cand   = (float4*)(ws + 16384);

  hipMemsetAsync(ws + 4096, 0, 4 + 4 * IBLOCKS, stream);
  fused_kernel<<<IBLOCKS * CHUNKS, 256, 0, stream>>>(pred, targ, feat, pts,
                                                     part, done, ticket, featp,
                                                     cand, out);
}

// Round 5
// 103.476 us; speedup vs baseline: 3.2943x; 3.2943x over previous
//
#include <hip/hip_runtime.h>
#include <float.h>
#include <math.h>

// AdvancedLossFunction: total = 1.0*occ + 0.1*smooth + 0.01*sparse + 0.1*cons
// R18: REVERT fusion (R17 fused kernel = 335us pure stall: all-thread
//   device-scope __threadfence by 2048 blocks -> L2 writeback/invalidate storm,
//   28 GB/s, VALUBusy 7.5%. Cross-XCD producer->consumer inside one grid is
//   strictly worse than a kernel boundary here). Two dispatches again.
// KEEP R17's knn win: 32-j candidate group == one MFMA tile. Per tile:
//   balanced 16-way min over acc regs, 1 key pack, 1 ins4f (~14 VALU/tile vs
//   R16's ~22). Group id = j/32, 9 bits (512 groups) -> key keeps 23 value
//   bits. Cross-half dedup (keep min of dup ids) as R15/R16; coverage proof
//   unchanged: {self,NN1..3} occupy <=4 groups; keys <= t(NN3) are in each
//   half's top-4; distinct-id top-4 of merged 8 covers. absmax 0 historically.
// merge: R16 wave-parallel structure; wave sub evaluates group qarr[sub]'s
//   32 candidates (exact d2, self-excl) -> per-wave top-3 -> LDS -> wave 0
//   merges 12 -> scalars. part/done last-block final reduction (proven).
// Fill ~40.5us is harness ws poison (uncontrollable); fills are the clock.

constexpr int   N_ = 16384;
constexpr int   F_ = 64;
constexpr float OCC_W = 1.0f, SMOOTH_W = 0.1f, SPARSE_W = 0.01f, CONS_W = 0.1f;
constexpr float EPS_ = 1e-7f;

constexpr int CHUNKS  = 16;
constexpr int CHUNK_J = N_ / CHUNKS;    // 1024 j's per chunk
constexpr int JTILES  = CHUNK_J / 32;   // 32 tiles = 32 groups per chunk
constexpr int IB      = 128;            // i's per block (4 waves x 32)
constexpr int IBLOCKS = N_ / IB;        // 128

typedef __attribute__((ext_vector_type(8)))  short bf16x8;
typedef __attribute__((ext_vector_type(16))) float f32x16;

union U128 { uint4 u; bf16x8 s; };

__device__ __forceinline__ void ins4f(float t, float& b0, float& b1, float& b2, float& b3) {
  // maintains b0<=b1<=b2<=b3
  float n0 = fminf(b0, t);
  float n1 = __builtin_amdgcn_fmed3f(b0, b1, t);
  float n2 = __builtin_amdgcn_fmed3f(b1, b2, t);
  float n3 = __builtin_amdgcn_fmed3f(b2, b3, t);
  b0 = n0; b1 = n1; b2 = n2; b3 = n3;
}

// RNE split x = hi + lo (both bf16); returns 16-bit payloads.
__device__ __forceinline__ void split2(float x, unsigned& h16, unsigned& l16) {
  unsigned u = __float_as_uint(x);
  unsigned r = u + 0x7FFFu + ((u >> 16) & 1u);
  h16 = r >> 16;
  float lo = x - __uint_as_float(r & 0xFFFF0000u);
  unsigned v = __float_as_uint(lo);
  l16 = (v + 0x7FFFu + ((v >> 16) & 1u)) >> 16;
}

// ws layout: 0: float4 part[256] | 4096: unsigned done | 8192: float4 cand[CHUNKS][N]

__global__ __launch_bounds__(256) void knn_mfma(const float* __restrict__ pts,
                                                float4* __restrict__ cand,
                                                unsigned* __restrict__ done) {
  if (blockIdx.x == 0 && threadIdx.x == 0) *done = 0u;
  __shared__ uint4 AF[2][CHUNK_J];      // packed A-frag halves, 32 KB
  const int tid   = threadIdx.x;
  const int chunk = blockIdx.x & (CHUNKS - 1);
  const int ibk   = blockIdx.x >> 4;    // log2(CHUNKS)
  const int j0    = chunk * CHUNK_J;

  // Stage j-side fragments: per j, Kvec as 8 packed words (2 bf16 each).
  for (int t = tid; t < CHUNK_J; t += 256) {
    int j = j0 + t;
    float qx = pts[3 * j], qy = pts[3 * j + 1], qz = pts[3 * j + 2];
    float w  = fmaf(qx, qx, fmaf(qy, qy, qz * qz));
    unsigned Hx, Lx, Hy, Ly, Hz, Lz, Hw, Lw;
    split2(-2.f * qx, Hx, Lx);
    split2(-2.f * qy, Hy, Ly);
    split2(-2.f * qz, Hz, Lz);
    split2(w, Hw, Lw);
    AF[0][t] = make_uint4(Hx | (Hx << 16), Lx | (Lx << 16),
                          Hy | (Hy << 16), Ly | (Ly << 16));
    AF[1][t] = make_uint4(Hz | (Hz << 16), Lz | (Lz << 16),
                          Hw | (Lw << 16), 0u);
  }

  // i-side (B operand) fragment: resident for the whole kernel.
  const int lane = tid & 63, wv = tid >> 6;
  const int h = lane >> 5, il = lane & 31;
  const int i = ibk * IB + wv * 32 + il;
  U128 bfr;
  {
    float x = pts[3 * i], y = pts[3 * i + 1], z = pts[3 * i + 2];
    unsigned hx, lx, hy, ly, hz, lz;
    split2(x, hx, lx);
    split2(y, hy, ly);
    split2(z, hz, lz);
    if (h == 0) {
      unsigned a = hx | (lx << 16), c = hy | (ly << 16);
      bfr.u = make_uint4(a, a, c, c);
    } else {
      unsigned a = hz | (lz << 16);
      bfr.u = make_uint4(a, a, 0x3F803F80u, 0u);   // bf16(1.0) pair
    }
  }
  __syncthreads();

  float b0 = FLT_MAX, b1 = FLT_MAX, b2 = FLT_MAX, b3 = FLT_MAX;
  const f32x16 zacc = {};                          // loop-invariant zero C operand
  const unsigned idb = (unsigned)(chunk * JTILES); // group id base, 9 bits total
  const uint4* __restrict__ afp = &AF[h][0];

#pragma unroll 4
  for (int t = 0; t < JTILES; ++t) {
    U128 af; af.u = afp[t * 32 + il];              // conflict-free b128
    f32x16 acc = __builtin_amdgcn_mfma_f32_32x32x16_bf16(af.s, bfr.s, zacc, 0, 0, 0);
    // balanced 16-way min over this lane-half's 16 rows of the tile
    float u0 = fminf(acc[0],  acc[1]),  u1 = fminf(acc[2],  acc[3]);
    float u2 = fminf(acc[4],  acc[5]),  u3 = fminf(acc[6],  acc[7]);
    float u4 = fminf(acc[8],  acc[9]),  u5 = fminf(acc[10], acc[11]);
    float u6 = fminf(acc[12], acc[13]), u7 = fminf(acc[14], acc[15]);
    float v0 = fminf(u0, u1), v1 = fminf(u2, u3);
    float v2 = fminf(u4, u5), v3 = fminf(u6, u7);
    float m  = fminf(fminf(v0, v1), fminf(v2, v3));
    float kf = __uint_as_float((__float_as_uint(m) & 0xFFFFFE00u) | (idb + (unsigned)t));
    ins4f(kf, b0, b1, b2, b3);
  }

  // Cross-half merge: halves hold partial minima over disjoint ROW subsets of
  // the SAME group ids -> dedup: keep smaller of dup pair, re-sort 8 -> top-4.
  {
    float o0 = __shfl_xor(b0, 32), o1 = __shfl_xor(b1, 32),
          o2 = __shfl_xor(b2, 32), o3 = __shfl_xor(b3, 32);
    float B[4] = {b0, b1, b2, b3};
    float O[4] = {o0, o1, o2, o3};
    unsigned ibd[4], iod[4];
#pragma unroll
    for (int k = 0; k < 4; ++k) {
      ibd[k] = __float_as_uint(B[k]) & 0x1FFu;
      iod[k] = __float_as_uint(O[k]) & 0x1FFu;
    }
#pragma unroll
    for (int k = 0; k < 4; ++k) {
#pragma unroll
      for (int m = 0; m < 4; ++m) {
        bool dup = (iod[k] == ibd[m]);
        bool om  = dup && (O[k] >= B[m]);
        bool bm  = dup && (O[k] <  B[m]);
        if (om) O[k] = FLT_MAX;
        if (bm) B[m] = FLT_MAX;
      }
    }
    b0 = b1 = b2 = b3 = FLT_MAX;
#pragma unroll
    for (int k = 0; k < 4; ++k) ins4f(B[k], b0, b1, b2, b3);
#pragma unroll
    for (int k = 0; k < 4; ++k) ins4f(O[k], b0, b1, b2, b3);
  }
  if (h == 0) cand[(size_t)chunk * N_ + i] = make_float4(b0, b1, b2, b3);
}

// grid 256: 64 i's per block; sub-wave w reduces 4 chunks -> sh; ALL waves
// rebuild merged top-4 group list; wave w evaluates group qarr[w] (32 exact-d2
// candidates) -> per-wave top-3 (d2,pred) -> LDS -> wave 0 merges 12 -> top-3.
__global__ __launch_bounds__(256) void merge_kernel(const float* __restrict__ pred,
                                                    const float* __restrict__ targ,
                                                    const float* __restrict__ feat,
                                                    const float* __restrict__ pts,
                                                    const float4* __restrict__ cand,
                                                    float4* __restrict__ part,
                                                    unsigned* __restrict__ done,
                                                    float* __restrict__ out) {
  __shared__ float4 sh[256];
  __shared__ float2 t3[4][3][64];
  __shared__ float ws4[4][4];
  __shared__ int is_last;
  constexpr int CPT = CHUNKS / 4;                  // 4 chunks per sub-wave
  int tid  = threadIdx.x;
  int lane = tid & 63;
  int sub  = tid >> 6;
  int i = blockIdx.x * 64 + lane;

  const float4* f4 = (const float4*)feat;
  float s_sp = 0.f;
#pragma unroll
  for (int s = 0; s < 4; ++s) {
    float4 v = f4[(size_t)s * 65536 + blockIdx.x * 256 + tid];
    s_sp += fabsf(v.x) + fabsf(v.y) + fabsf(v.z) + fabsf(v.w);
  }

  // Phase B: per-sub top-4 over its 4 chunks.
  float b0 = FLT_MAX, b1 = FLT_MAX, b2 = FLT_MAX, b3 = FLT_MAX;
#pragma unroll
  for (int cc = 0; cc < CPT; ++cc) {
    float4 v = cand[(size_t)(sub * CPT + cc) * N_ + i];
    ins4f(v.x, b0, b1, b2, b3);
    ins4f(v.y, b0, b1, b2, b3);
    ins4f(v.z, b0, b1, b2, b3);
    ins4f(v.w, b0, b1, b2, b3);
  }
  sh[tid] = make_float4(b0, b1, b2, b3);
  __syncthreads();

  // Phase C (all waves, identical): merge 4 sub-vectors -> top-4 group ids.
  // Ids globally distinct across the 4 vectors (chunk-disjoint + knn dedup).
  b0 = b1 = b2 = b3 = FLT_MAX;
#pragma unroll
  for (int w = 0; w < 4; ++w) {
    float4 v = sh[w * 64 + lane];
    ins4f(v.x, b0, b1, b2, b3);
    ins4f(v.y, b0, b1, b2, b3);
    ins4f(v.z, b0, b1, b2, b3);
    ins4f(v.w, b0, b1, b2, b3);
  }
  unsigned qsel;
  {
    float bsel = sub == 0 ? b0 : (sub == 1 ? b1 : (sub == 2 ? b2 : b3));
    qsel = __float_as_uint(bsel) & 0x1FFu;
  }

  // Phase D: wave `sub` evaluates its group's 32 candidates, exact d2.
  float xi = pts[3 * i], yi = pts[3 * i + 1], zi = pts[3 * i + 2];
  float c0 = FLT_MAX, c1 = FLT_MAX, c2 = FLT_MAX;
  float p0 = 0.f, p1 = 0.f, p2 = 0.f;
#pragma unroll 8
  for (int m = 0; m < 32; ++m) {
    int j = (int)(qsel * 32 + m);
    float dx = xi - pts[3 * j], dy = yi - pts[3 * j + 1], dz = zi - pts[3 * j + 2];
    float d2 = fmaf(dx, dx, fmaf(dy, dy, dz * dz));
    float pj = pred[j];
    if (j != i && d2 < c2) {                       // exact top-3, self excluded
      bool cc0 = d2 < c0, cc1 = d2 < c1;
      float n2 = cc1 ? c1 : d2;               float m2 = cc1 ? p1 : pj;
      float n1 = cc0 ? c0 : (cc1 ? d2 : c1);  float m1 = cc0 ? p0 : (cc1 ? pj : p1);
      float n0 = cc0 ? d2 : c0;               float m0 = cc0 ? pj : p0;
      c0 = n0; c1 = n1; c2 = n2; p0 = m0; p1 = m1; p2 = m2;
    }
  }
  t3[sub][0][lane] = make_float2(c0, p0);
  t3[sub][1][lane] = make_float2(c1, p1);
  t3[sub][2][lane] = make_float2(c2, p2);
  __syncthreads();

  // Phase E: wave 0 merges the 4 waves' top-3 -> global top-3 -> scalars.
  float s_occ = 0.f, s_cons = 0.f, s_sm = 0.f;
  if (sub == 0) {
#pragma unroll
    for (int w = 1; w < 4; ++w) {
#pragma unroll
      for (int r = 0; r < 3; ++r) {
        float2 e = t3[w][r][lane];
        float d2 = e.x, pj = e.y;
        if (d2 < c2) {
          bool cc0 = d2 < c0, cc1 = d2 < c1;
          float n2 = cc1 ? c1 : d2;               float m2 = cc1 ? p1 : pj;
          float n1 = cc0 ? c0 : (cc1 ? d2 : c1);  float m1 = cc0 ? p0 : (cc1 ? pj : p1);
          float n0 = cc0 ? d2 : c0;               float m0 = cc0 ? pj : p0;
          c0 = n0; c1 = n1; c2 = n2; p0 = m0; p1 = m1; p2 = m2;
        }
      }
    }
    float pi = pred[i], tg = targ[i];
    float p  = fminf(fmaxf(pi, EPS_), 1.0f - EPS_);
    s_occ  = -(tg * __logf(p) + (1.0f - tg) * __logf(1.0f - p));
    float dd = pi - tg;
    s_cons = dd * dd;
    s_sm   = fabsf(pi - p0) + fabsf(pi - p1) + fabsf(pi - p2);
  }

  for (int off = 32; off > 0; off >>= 1) {
    s_sp   += __shfl_down(s_sp, off);
    s_occ  += __shfl_down(s_occ, off);
    s_cons += __shfl_down(s_cons, off);
    s_sm   += __shfl_down(s_sm, off);
  }
  if ((tid & 63) == 0) {
    int w = tid >> 6;
    ws4[w][0] = s_occ; ws4[w][1] = s_cons; ws4[w][2] = s_sp; ws4[w][3] = s_sm;
  }
  __syncthreads();
  if (tid == 0) {
    part[blockIdx.x] = make_float4(ws4[0][0] + ws4[1][0] + ws4[2][0] + ws4[3][0],
                                   ws4[0][1] + ws4[1][1] + ws4[2][1] + ws4[3][1],
                                   ws4[0][2] + ws4[1][2] + ws4[2][2] + ws4[3][2],
                                   ws4[0][3] + ws4[1][3] + ws4[2][3] + ws4[3][3]);
    __threadfence();
    unsigned prev = atomicAdd(done, 1u);
    is_last = (prev == (unsigned)(gridDim.x - 1));
  }
  __syncthreads();

  if (is_last) {
    __threadfence();
    float4 a = part[tid];
    float o = a.x, cn = a.y, sp = a.z, sm = a.w;
    for (int off = 32; off > 0; off >>= 1) {
      o  += __shfl_down(o, off);
      cn += __shfl_down(cn, off);
      sp += __shfl_down(sp, off);
      sm += __shfl_down(sm, off);
    }
    if ((tid & 63) == 0) {
      int w = tid >> 6;
      ws4[w][0] = o; ws4[w][1] = cn; ws4[w][2] = sp; ws4[w][3] = sm;
    }
    __syncthreads();
    if (tid == 0) {
      float occ  = ws4[0][0] + ws4[1][0] + ws4[2][0] + ws4[3][0];
      float cons = ws4[0][1] + ws4[1][1] + ws4[2][1] + ws4[3][1];
      float spar = ws4[0][2] + ws4[1][2] + ws4[2][2] + ws4[3][2];
      float smoo = ws4[0][3] + ws4[1][3] + ws4[2][3] + ws4[3][3];
      out[0] = OCC_W * (occ / (float)N_)
             + CONS_W * (cons / (float)N_)
             + SPARSE_W * (spar / (float)(N_ * F_))
             + SMOOTH_W * (smoo / (float)(N_ * 3));
    }
  }
}

extern "C" void kernel_launch(void* const* d_in, const int* in_sizes, int n_in,
                              void* d_out, int out_size, void* d_ws, size_t ws_size,
                              hipStream_t stream) {
  const float* pred = (const float*)d_in[0];
  const float* targ = (const float*)d_in[1];
  const float* feat = (const float*)d_in[2];
  const float* pts  = (const float*)d_in[3];
  float* out = (float*)d_out;

  char*     ws   = (char*)d_ws;
  float4*   part = (float4*)ws;
  unsigned* done = (unsigned*)(ws + 4096);
  float4*   cand = (float4*)(ws + 8192);

  knn_mfma<<<IBLOCKS * CHUNKS, 256, 0, stream>>>(pts, cand, done);
  merge_kernel<<<256, 256, 0, stream>>>(pred, targ, feat, pts, cand, part, done, out);
}